// Round 3
// baseline (1935.144 us; speedup 1.0000x reference)
//
#include <hip/hip_runtime.h>

// GRU decoder, bf16 MFMA, 16 waves/block (4 waves/SIMD for latency hiding).
// Block owns BM=32 rows for all T=96 steps. Wave w owns h-cols [w*16,w*16+16)
// across all 3 gates (3 B-frags per kt). Wk (K=64) resident in registers;
// prev_out rank-1 term computed in fp32 VALU epilogue. Wr streamed from L2.
// h carried fp32 in registers; bf16 copy in LDS for next step's A-frags.
// out accumulated in LDS, dumped coalesced at the end. 2 barriers/step.

#define Bdim 8192
#define Tdim 96
#define Fdim 64
#define Hdim 256
#define BM   32
#define XS   72    // feat row stride (bf16): 64 + 8 pad -> 144 B
#define HS   264   // h row stride: 256 + 8 pad -> 528 B
#define OS   97    // outbuf row stride (floats), +1 pad vs 96

typedef __attribute__((ext_vector_type(8))) short s16x8;
typedef __attribute__((ext_vector_type(4))) float f32x4;

#define MFMA __builtin_amdgcn_mfma_f32_16x16x32_bf16

__device__ __forceinline__ unsigned short f2bf(float f) {
    union { float f; unsigned u; } v; v.f = f;
    unsigned r = v.u + 0x7FFFu + ((v.u >> 16) & 1u);   // RNE
    return (unsigned short)(r >> 16);
}

// ---- one-time weight conversion + B-fragment swizzle ----
// frag f, lane l: 8 bf16 at [f*512 + l*8]; lane holds
// B[k = kt*32 + (l>>4)*8 + j][n = g*256 + w*16 + (l&15)]
// sR: f = (w*8 + kt)*3 + g   (w 0..15, kt 0..7, g 0..2)  -> 384 frags
// sK: f = (w*2 + kt)*3 + g   (kt 0..1), source rows Wk[1+k] -> 96 frags
__global__ void prep_swz(const float* __restrict__ Wk, const float* __restrict__ Wr,
                         unsigned short* __restrict__ sK, unsigned short* __restrict__ sR) {
    int idx = blockIdx.x * blockDim.x + threadIdx.x;
    int lane = idx & 63;
    int q = lane >> 4, cc = lane & 15;
    if (idx < 24576) {                       // sR
        int f = idx >> 6;
        int g = f % 3; int rest = f / 3;
        int kt = rest & 7; int w = rest >> 3;
        int n = g * 256 + w * 16 + cc;
        unsigned short* d = sR + (size_t)idx * 8;
#pragma unroll
        for (int j = 0; j < 8; ++j)
            d[j] = f2bf(Wr[(size_t)(kt * 32 + q * 8 + j) * 768 + n]);
    } else if (idx < 24576 + 6144) {         // sK
        int i2 = idx - 24576;
        int f = i2 >> 6;
        int g = f % 3; int rest = f / 3;
        int kt = rest & 1; int w = rest >> 1;
        int n = g * 256 + w * 16 + cc;
        unsigned short* d = sK + (size_t)i2 * 8;
#pragma unroll
        for (int j = 0; j < 8; ++j)
            d[j] = f2bf(Wk[(size_t)(1 + kt * 32 + q * 8 + j) * 768 + n]);
    }
}

__launch_bounds__(1024, 4)
__global__ void gru_mfma2(
    const float* __restrict__ feat,       // [B,T,F]
    const float* __restrict__ init_state, // [B,H]
    const float* __restrict__ init_inp,   // [B,1]
    const unsigned short* __restrict__ sK,
    const unsigned short* __restrict__ sR,
    const float* __restrict__ Wk,         // for row 0 (prev_out rank-1 term)
    const float* __restrict__ ib, const float* __restrict__ rb,
    const float* __restrict__ dw, const float* __restrict__ db,
    float* __restrict__ out)              // [B,T,1]
{
    __shared__ __align__(16) unsigned short xs[BM * XS];  // feat tile, bf16
    __shared__ __align__(16) unsigned short hs[BM * HS];  // h state, bf16
    __shared__ float wpart[16][BM];
    __shared__ float outbuf[BM * OS];

    const int tid  = threadIdx.x;
    const int lane = tid & 63;
    const int w    = tid >> 6;     // wave 0..15: h-cols [w*16, w*16+16)
    const int q    = lane >> 4;
    const int c    = lane & 15;
    const int b0   = blockIdx.x * BM;

    const int colh = w * 16 + c;
    const float bz   = ib[colh]       + rb[colh];
    const float brr  = ib[256 + colh] + rb[256 + colh];
    const float bxh  = ib[512 + colh];
    const float bhh  = rb[512 + colh];
    const float wk0z = Wk[colh], wk0r = Wk[256 + colh], wk0h = Wk[512 + colh];
    const float dwv  = dw[colh];
    const float dbv  = db[0];

    // init h: fp32 in regs + bf16 in LDS
    float hreg[2][4];
    float prevreg[2][4];
#pragma unroll
    for (int mt = 0; mt < 2; ++mt)
#pragma unroll
        for (int i = 0; i < 4; ++i) {
            int row = mt * 16 + q * 4 + i;
            float v = init_state[(size_t)(b0 + row) * Hdim + colh];
            hreg[mt][i] = v;
            hs[row * HS + colh] = f2bf(v);
            prevreg[mt][i] = init_inp[b0 + row];
        }

    // stage feat t=0 (512 threads: 32 rows x 16 float4)
    if (tid < 512) {
        int r = tid >> 4, fi = tid & 15;
        float4 f = *(const float4*)&feat[((size_t)(b0 + r) * Tdim + 0) * Fdim + fi * 4];
        ushort4 p; p.x = f2bf(f.x); p.y = f2bf(f.y); p.z = f2bf(f.z); p.w = f2bf(f.w);
        *(ushort4*)&xs[r * XS + fi * 4] = p;
    }

    // Wk fragments resident (2 kt x 3 g = 6 frags = 24 VGPR)
    s16x8 wkr[2][3];
    {
        const unsigned short* kp = sK + (size_t)(w * 6) * 512 + lane * 8;
#pragma unroll
        for (int kt = 0; kt < 2; ++kt)
#pragma unroll
            for (int g = 0; g < 3; ++g)
                wkr[kt][g] = *(const s16x8*)(kp + (kt * 3 + g) * 512);
    }
    const unsigned short* wrp = sR + (size_t)(w * 24) * 512 + lane * 8;

    __syncthreads();

    for (int t = 0; t < Tdim; ++t) {
        // (a) finish step t-1's dense output; broadcast prev_out
        if (t > 0) {
            int r = lane & 31;
            float s = dbv;
#pragma unroll
            for (int ww = 0; ww < 16; ++ww) s += wpart[ww][r];
            if (w == 0 && lane < 32) outbuf[r * OS + (t - 1)] = s;
#pragma unroll
            for (int mt = 0; mt < 2; ++mt)
#pragma unroll
                for (int i = 0; i < 4; ++i)
                    prevreg[mt][i] = __shfl(s, mt * 16 + q * 4 + i, 64);
        }

        // (b) GEMMs
        f32x4 az[2], arr[2], axh[2], ahh[2];
#pragma unroll
        for (int mt = 0; mt < 2; ++mt) {
            az[mt] = (f32x4)0.0f; arr[mt] = (f32x4)0.0f;
            axh[mt] = (f32x4)0.0f; ahh[mt] = (f32x4)0.0f;
        }

#pragma unroll
        for (int kt = 0; kt < 2; ++kt) {     // feat GEMM, K=64, weights in regs
            s16x8 a0 = *(const s16x8*)&xs[c * XS + kt * 32 + q * 8];
            s16x8 a1 = *(const s16x8*)&xs[(16 + c) * XS + kt * 32 + q * 8];
            az[0]  = MFMA(a0, wkr[kt][0], az[0], 0, 0, 0);
            az[1]  = MFMA(a1, wkr[kt][0], az[1], 0, 0, 0);
            arr[0] = MFMA(a0, wkr[kt][1], arr[0], 0, 0, 0);
            arr[1] = MFMA(a1, wkr[kt][1], arr[1], 0, 0, 0);
            axh[0] = MFMA(a0, wkr[kt][2], axh[0], 0, 0, 0);
            axh[1] = MFMA(a1, wkr[kt][2], axh[1], 0, 0, 0);
        }

#pragma unroll
        for (int kt = 0; kt < 8; ++kt) {     // h GEMM, K=256, weights from L2
            s16x8 bzf = *(const s16x8*)(wrp + (size_t)(kt * 3 + 0) * 512);
            s16x8 brf = *(const s16x8*)(wrp + (size_t)(kt * 3 + 1) * 512);
            s16x8 bhf = *(const s16x8*)(wrp + (size_t)(kt * 3 + 2) * 512);
            s16x8 a0 = *(const s16x8*)&hs[c * HS + kt * 32 + q * 8];
            s16x8 a1 = *(const s16x8*)&hs[(16 + c) * HS + kt * 32 + q * 8];
            az[0]  = MFMA(a0, bzf, az[0], 0, 0, 0);
            az[1]  = MFMA(a1, bzf, az[1], 0, 0, 0);
            arr[0] = MFMA(a0, brf, arr[0], 0, 0, 0);
            arr[1] = MFMA(a1, brf, arr[1], 0, 0, 0);
            ahh[0] = MFMA(a0, bhf, ahh[0], 0, 0, 0);
            ahh[1] = MFMA(a1, bhf, ahh[1], 0, 0, 0);
        }
        __syncthreads();   // S1: all hs/xs reads of this step done

        // (d) epilogue: gates, h update, dense partials
#pragma unroll
        for (int mt = 0; mt < 2; ++mt) {
            float sd[4];
#pragma unroll
            for (int i = 0; i < 4; ++i) {
                float pv = prevreg[mt][i];
                float zz = 1.0f / (1.0f + __expf(-(az[mt][i] + bz + pv * wk0z)));
                float rr = 1.0f / (1.0f + __expf(-(arr[mt][i] + brr + pv * wk0r)));
                float cd = tanhf(axh[mt][i] + bxh + pv * wk0h +
                                 rr * (ahh[mt][i] + bhh));
                float hn = zz * hreg[mt][i] + (1.0f - zz) * cd;
                hreg[mt][i] = hn;
                hs[(mt * 16 + q * 4 + i) * HS + colh] = f2bf(hn);
                sd[i] = hn * dwv;
            }
#pragma unroll
            for (int i = 0; i < 4; ++i) {
                float s = sd[i];
                s += __shfl_xor(s, 1, 64);
                s += __shfl_xor(s, 2, 64);
                s += __shfl_xor(s, 4, 64);
                s += __shfl_xor(s, 8, 64);
                if (c == 0) wpart[w][mt * 16 + q * 4 + i] = s;
            }
        }

        // stage feat t+1 (xs reads for step t finished at S1)
        if (t + 1 < Tdim && tid < 512) {
            int r = tid >> 4, fi = tid & 15;
            float4 f = *(const float4*)&feat[((size_t)(b0 + r) * Tdim + (t + 1)) * Fdim + fi * 4];
            ushort4 p; p.x = f2bf(f.x); p.y = f2bf(f.y); p.z = f2bf(f.z); p.w = f2bf(f.w);
            *(ushort4*)&xs[r * XS + fi * 4] = p;
        }
        __syncthreads();   // S2: hs/wpart/xs writes visible
    }

    // final dense output for t=95
    {
        int r = lane & 31;
        float s = dbv;
#pragma unroll
        for (int ww = 0; ww < 16; ++ww) s += wpart[ww][r];
        if (w == 0 && lane < 32) outbuf[r * OS + (Tdim - 1)] = s;
    }
    __syncthreads();

    // coalesced dump: out[(b0+r)*96 + tt]
    for (int i = tid; i < BM * Tdim; i += 1024) {
        int r = i / Tdim, tt = i - r * Tdim;
        out[(size_t)b0 * Tdim + i] = outbuf[r * OS + tt];
    }
}

extern "C" void kernel_launch(void* const* d_in, const int* in_sizes, int n_in,
                              void* d_out, int out_size, void* d_ws, size_t ws_size,
                              hipStream_t stream) {
    const float* feat       = (const float*)d_in[0];
    const float* init_state = (const float*)d_in[1];
    const float* init_inp   = (const float*)d_in[2];
    const float* Wk         = (const float*)d_in[3];
    const float* Wr         = (const float*)d_in[4];
    const float* ib         = (const float*)d_in[5];
    const float* rb         = (const float*)d_in[6];
    const float* dw         = (const float*)d_in[7];
    const float* db         = (const float*)d_in[8];
    float* out              = (float*)d_out;

    unsigned short* sR = (unsigned short*)d_ws;                        // 384 frags * 1 KB
    unsigned short* sK = (unsigned short*)((char*)d_ws + 24576 * 16);  // 96 frags * 1 KB

    prep_swz<<<120, 256, 0, stream>>>(Wk, Wr, sK, sR);
    gru_mfma2<<<Bdim / BM, 1024, 0, stream>>>(
        feat, init_state, init_inp, sK, sR, Wk, ib, rb, dw, db, out);
}